// Round 5
// baseline (351.239 us; speedup 1.0000x reference)
//
#include <hip/hip_runtime.h>
#include <hip/hip_bf16.h>

#define B_   4
#define N_   2048
#define IN_  256
#define OUT_ 256
#define H_   4
#define HD_  64
#define LN_EPS 1e-5f

typedef __bf16 bf16x8 __attribute__((ext_vector_type(8)));
typedef float  f32x4  __attribute__((ext_vector_type(4)));
typedef unsigned short u16x8 __attribute__((ext_vector_type(8)));
typedef unsigned int   u32x2 __attribute__((ext_vector_type(2)));
typedef unsigned int   u32x4 __attribute__((ext_vector_type(4)));

__device__ __forceinline__ unsigned short f2bf(float x) {
    unsigned int u = __float_as_uint(x);
    return (unsigned short)((u + 0x7FFFu + ((u >> 16) & 1u)) >> 16);
}
__device__ __forceinline__ float bf2f(unsigned short u) {
    return __uint_as_float((unsigned int)u << 16);
}
__device__ __forceinline__ unsigned int cvtpk(float lo, float hi) {
    unsigned int r;
    asm("v_cvt_pk_bf16_f32 %0, %1, %2" : "=v"(r) : "v"(lo), "v"(hi));
    return r;
}

// ---------------------------------------------------------------------------
// conv: nf -> bf16 (nfb), W_{lin,q,k} -> bf16 transposed (Wt[z][n][k])
// ---------------------------------------------------------------------------
__global__ __launch_bounds__(256) void conv_kernel(
    const float* __restrict__ nf, const float* __restrict__ Wl,
    const float* __restrict__ Wq, const float* __restrict__ Wk,
    unsigned short* __restrict__ nfb, unsigned short* __restrict__ Wt)
{
    const int bid = blockIdx.x, tid = threadIdx.x;
    if (bid < 1024) {
        size_t i = ((size_t)bid * 256 + tid) * 8;
        u16x8 o;
        #pragma unroll
        for (int j = 0; j < 8; j++) o[j] = f2bf(nf[i + j]);
        *(u16x8*)&nfb[i] = o;
    } else {
        int t = (bid - 1024) * 256 + tid;   // 0..196607
        int z = t >> 16;
        int l = t & 65535;
        int k = l & 255, n = l >> 8;
        const float* W = (z == 0) ? Wl : (z == 1 ? Wq : Wk);
        Wt[(size_t)z * 65536 + n * 256 + k] = f2bf(W[k * 256 + n]);
    }
}

// ---------------------------------------------------------------------------
// gemm3: X/q/k = lrelu(nfb @ W + bias), barrier-free fragment GEMM
// ---------------------------------------------------------------------------
__global__ __launch_bounds__(256) void gemm3_kernel(
    const unsigned short* __restrict__ nfb, const unsigned short* __restrict__ Wt3,
    const float* __restrict__ bl,
    unsigned short* __restrict__ qb, unsigned short* __restrict__ kb,
    unsigned short* __restrict__ Xt)
{
    const int z  = blockIdx.z;
    const int m0 = blockIdx.x * 64, n0 = blockIdx.y * 64;
    const int tid = threadIdx.x, wave = tid >> 6, lane = tid & 63;
    const int lq = lane >> 4, lr = lane & 15;
    const unsigned short* Wt = Wt3 + (size_t)z * 65536;

    f32x4 acc[4] = {};
    #pragma unroll 4
    for (int k0 = 0; k0 < IN_; k0 += 32) {
        bf16x8 af = *(const bf16x8*)&nfb[(size_t)(m0 + wave * 16 + lr) * IN_ + k0 + lq * 8];
        #pragma unroll
        for (int f = 0; f < 4; f++) {
            bf16x8 bfr = *(const bf16x8*)&Wt[(size_t)(n0 + f * 16 + lr) * IN_ + k0 + lq * 8];
            acc[f] = __builtin_amdgcn_mfma_f32_16x16x32_bf16(af, bfr, acc[f], 0, 0, 0);
        }
    }

    #pragma unroll
    for (int f = 0; f < 4; f++) {
        int c = n0 + f * 16 + lr;
        float bias = (z == 0) ? bl[c] : 0.0f;
        #pragma unroll
        for (int r = 0; r < 4; r++) {
            int m = m0 + wave * 16 + lq * 4 + r;
            float v = acc[f][r] + bias;
            v = (v >= 0.f) ? v : 0.01f * v;
            unsigned short bv = f2bf(v);
            if (z == 0) {
                int n = m & (N_ - 1);
                int h = c >> 6, d = c & 63;
                Xt[(((size_t)(m >> 11) * H_ + h) * HD_ + d) * N_ + n] = bv;
            } else {
                unsigned short* dst = (z == 1) ? qb : kb;
                dst[(size_t)m * OUT_ + c] = bv;
            }
        }
    }
}

// ---------------------------------------------------------------------------
// att: W[s][x][y] = adj*sigmoid(q.k/8) (bf16) + row-sum partials.
// 128x128 tile/block, 4 waves 2x2. adj staged bf16 in LDS; w overwrites it
// in place; coalesced 16B/lane store phase.
// ---------------------------------------------------------------------------
__global__ __launch_bounds__(256, 4) void att_kernel(
    const float* __restrict__ adj,
    const unsigned short* __restrict__ qb,
    const unsigned short* __restrict__ kb,
    unsigned short* __restrict__ W,      // chunk: [s_local][N][N]
    float* __restrict__ degp,            // [32][SH][N]
    int b_base, int SH)
{
    const int s  = blockIdx.z;
    const int bg = b_base + (s >> 2);
    const int hg = s & 3;
    const int x0 = blockIdx.x * 128, y0 = blockIdx.y * 128;
    const int tid = threadIdx.x, wave = tid >> 6, lane = tid & 63;
    const int lq = lane >> 4, lr = lane & 15;
    const int wq = wave >> 1, wn = wave & 1;
    const int wx0 = wq * 64, wy0 = wn * 64;           // local offsets
    const float sc = -0.125f * 1.44269504088896f;

    __shared__ unsigned short ads[128][136];

    // --- stage adj 128x128 f32 -> bf16 LDS (coalesced f32x4 loads) ---
    {
        const int row0 = tid >> 5;                    // 0..7
        const int col  = (tid & 31) * 4;              // 0..124
        const float* ap = adj + ((size_t)bg * N_ + x0 + row0) * N_ + y0 + col;
        #pragma unroll 4
        for (int i = 0; i < 16; i++) {
            f32x4 v = *(const f32x4*)(ap + (size_t)i * 8 * N_);
            u32x2 p = { cvtpk(v[0], v[1]), cvtpk(v[2], v[3]) };
            *(u32x2*)&ads[row0 + i * 8][col] = p;
        }
    }

    // --- QK^T MFMA (global frag loads, L2-resident q/k) ---
    const unsigned short* qrow = qb + (size_t)(bg * N_ + x0 + wx0) * OUT_ + hg * HD_;
    const unsigned short* krow = kb + (size_t)(bg * N_ + y0 + wy0) * OUT_ + hg * HD_;
    f32x4 acc[4][4] = {};
    #pragma unroll
    for (int ks = 0; ks < 2; ks++) {
        bf16x8 af[4];
        #pragma unroll
        for (int mf = 0; mf < 4; mf++)
            af[mf] = *(const bf16x8*)&qrow[(size_t)(mf * 16 + lr) * OUT_ + ks * 32 + lq * 8];
        #pragma unroll
        for (int nf = 0; nf < 4; nf++) {
            bf16x8 bfr = *(const bf16x8*)&krow[(size_t)(nf * 16 + lr) * OUT_ + ks * 32 + lq * 8];
            #pragma unroll
            for (int mf = 0; mf < 4; mf++)
                acc[mf][nf] = __builtin_amdgcn_mfma_f32_16x16x32_bf16(af[mf], bfr, acc[mf][nf], 0, 0, 0);
        }
    }
    __syncthreads();    // adj staged (covers all waves' ds_writes)

    // --- epilogue: w = adj*sigmoid, in-place in LDS, + row sums ---
    #pragma unroll
    for (int mf = 0; mf < 4; mf++) {
        #pragma unroll
        for (int r = 0; r < 4; r++) {
            const int xl = wx0 + mf * 16 + lq * 4 + r;
            float sum = 0.f;
            #pragma unroll
            for (int nf = 0; nf < 4; nf++) {
                const int yl = wy0 + nf * 16 + lr;
                float a = bf2f(ads[xl][yl]);
                float att = __builtin_amdgcn_rcpf(1.f + exp2f(acc[mf][nf][r] * sc));
                float wv = a * att;
                ads[xl][yl] = (unsigned short)cvtpk(wv, wv);
                sum += wv;
            }
            sum += __shfl_xor(sum, 1); sum += __shfl_xor(sum, 2);
            sum += __shfl_xor(sum, 4); sum += __shfl_xor(sum, 8);
            if (lr == 0)
                degp[((size_t)(blockIdx.y * 2 + wn) * SH + s) * N_ + x0 + xl] = sum;
        }
    }
    __syncthreads();    // all w values written

    // --- coalesced store: 16B/lane ---
    unsigned short* Wp = W + (size_t)s * N_ * N_;
    const int col = (tid & 15) * 8;
    const int r0  = tid >> 4;                         // 0..15
    #pragma unroll
    for (int i = 0; i < 8; i++) {
        int row = i * 16 + r0;
        u16x8 v = *(const u16x8*)&ads[row][col];
        *(u16x8*)&Wp[(size_t)(x0 + row) * N_ + y0 + col] = v;
    }
}

// ---------------------------------------------------------------------------
// degsum: deg = sum of 32 partials; dis = deg^-1/2
// ---------------------------------------------------------------------------
__global__ __launch_bounds__(256) void degsum_kernel(
    const float* __restrict__ degp, float* __restrict__ dis, int b_base, int SH)
{
    int t = blockIdx.x * 256 + threadIdx.x;    // SH*N threads
    int s = t >> 11, x = t & (N_ - 1);
    float sum = 0.f;
    #pragma unroll
    for (int j = 0; j < 32; j++) sum += degp[((size_t)j * SH + s) * N_ + x];
    dis[((size_t)b_base * H_ + s) * N_ + x] = (sum > 0.f) ? rsqrtf(sum) : 0.f;
}

// ---------------------------------------------------------------------------
// scale: Xs = Xt * dis_y (bf16); pointers pre-offset to chunk
// ---------------------------------------------------------------------------
__global__ __launch_bounds__(256) void scale_kernel(
    const unsigned short* __restrict__ Xt, const float* __restrict__ dis,
    unsigned short* __restrict__ Xs)
{
    int t = blockIdx.x * 256 + threadIdx.x;
    size_t idx = (size_t)t * 8;
    int s = t >> 14;                         // HD*N/8 = 16384
    int y = (int)(idx & (N_ - 1));
    f32x4 d0 = *(const f32x4*)&dis[(size_t)s * N_ + y];
    f32x4 d1 = *(const f32x4*)&dis[(size_t)s * N_ + y + 4];
    u16x8 x = *(const u16x8*)&Xt[idx];
    u32x4 o;
    o[0] = cvtpk(bf2f(x[0]) * d0[0], bf2f(x[1]) * d0[1]);
    o[1] = cvtpk(bf2f(x[2]) * d0[2], bf2f(x[3]) * d0[3]);
    o[2] = cvtpk(bf2f(x[4]) * d1[0], bf2f(x[5]) * d1[1]);
    o[3] = cvtpk(bf2f(x[6]) * d1[2], bf2f(x[7]) * d1[3]);
    *(u32x4*)&Xs[idx] = o;
}

// ---------------------------------------------------------------------------
// yout: Y = W @ Xs (K=2048), * dis_x, fused LayerNorm, write out.
// 1024-thread blocks: 16 waves = 4 heads x 4 d-quarters, one 16x16 frag each.
// 4 waves of a head share the streamed W rows (L1/L2 broadcast).
// ---------------------------------------------------------------------------
__global__ __launch_bounds__(1024, 8) void yout_kernel(
    const unsigned short* __restrict__ W,    // chunk base
    const unsigned short* __restrict__ Xs,   // chunk base
    const float* __restrict__ dis,           // full
    const float* __restrict__ lng, const float* __restrict__ lnb,
    float* __restrict__ out, int b_base)
{
    const int x0 = blockIdx.x * 16;
    const int bl = blockIdx.y;
    const int bg = b_base + bl;
    const int tid = threadIdx.x;
    const int wave = tid >> 6, lane = tid & 63;
    const int h = wave >> 2, dq = wave & 3;
    const int lq = lane >> 4, lr = lane & 15;
    const int s = bl * H_ + h;

    const unsigned short* Wp = W + (size_t)s * N_ * N_ + (size_t)(x0 + lr) * N_;
    const unsigned short* Xp = Xs + ((size_t)s * HD_ + dq * 16 + lr) * N_;

    f32x4 Y = {};
    for (int k0 = 0; k0 < N_; k0 += 128) {
        #pragma unroll
        for (int u = 0; u < 4; u++) {
            bf16x8 af = *(const bf16x8*)&Wp[k0 + u * 32 + lq * 8];
            bf16x8 xf = *(const bf16x8*)&Xp[k0 + u * 32 + lq * 8];
            Y = __builtin_amdgcn_mfma_f32_16x16x32_bf16(af, xf, Y, 0, 0, 0);
        }
    }

    float dx[4];
    #pragma unroll
    for (int r = 0; r < 4; r++)
        dx[r] = dis[((size_t)bg * H_ + h) * N_ + x0 + lq * 4 + r];

    __shared__ float lnred[2][16][16];
    float v[4];
    #pragma unroll
    for (int r = 0; r < 4; r++) {
        v[r] = Y[r] * dx[r];
        float a = v[r], q2 = v[r] * v[r];
        a += __shfl_xor(a, 1); a += __shfl_xor(a, 2); a += __shfl_xor(a, 4); a += __shfl_xor(a, 8);
        q2 += __shfl_xor(q2, 1); q2 += __shfl_xor(q2, 2); q2 += __shfl_xor(q2, 4); q2 += __shfl_xor(q2, 8);
        if (lr == 0) {
            lnred[0][wave][lq * 4 + r] = a;
            lnred[1][wave][lq * 4 + r] = q2;
        }
    }
    __syncthreads();

    const int c = h * HD_ + dq * 16 + lr;
    const float g = lng[c], bb = lnb[c];
    #pragma unroll
    for (int r = 0; r < 4; r++) {
        const int xr = lq * 4 + r;
        float t1 = 0.f, t2 = 0.f;
        #pragma unroll
        for (int wv = 0; wv < 16; wv++) { t1 += lnred[0][wv][xr]; t2 += lnred[1][wv][xr]; }
        float mu  = t1 * (1.f / 256.f);
        float var = t2 * (1.f / 256.f) - mu * mu;
        float rs  = rsqrtf(var + LN_EPS);
        out[((size_t)(bg * N_ + x0 + xr)) * OUT_ + c] = (v[r] - mu) * rs * g + bb;
    }
}

extern "C" void kernel_launch(void* const* d_in, const int* in_sizes, int n_in,
                              void* d_out, int out_size, void* d_ws, size_t ws_size,
                              hipStream_t stream) {
    const float* nf  = (const float*)d_in[0];
    const float* adj = (const float*)d_in[1];
    const float* Wl  = (const float*)d_in[2];
    const float* bl  = (const float*)d_in[3];
    const float* Wq  = (const float*)d_in[4];
    const float* Wk  = (const float*)d_in[5];
    const float* lng = (const float*)d_in[6];
    const float* lnb = (const float*)d_in[7];
    float* out = (float*)d_out;

    char* w = (char*)d_ws;
    unsigned short* nfb = (unsigned short*)w;  w += (size_t)B_ * N_ * IN_ * 2;
    unsigned short* Wt  = (unsigned short*)w;  w += (size_t)3 * IN_ * OUT_ * 2;
    unsigned short* qb  = (unsigned short*)w;  w += (size_t)B_ * N_ * OUT_ * 2;
    unsigned short* kb  = (unsigned short*)w;  w += (size_t)B_ * N_ * OUT_ * 2;
    unsigned short* Xt  = (unsigned short*)w;  w += (size_t)B_ * N_ * OUT_ * 2;
    unsigned short* Xs  = (unsigned short*)w;  w += (size_t)B_ * N_ * OUT_ * 2;
    float* dis = (float*)w;                    w += (size_t)B_ * H_ * N_ * 4;
    size_t fixed = (size_t)(w - (char*)d_ws);

    // nb batches per chunk: 4 if ws fits the full 134MB W buffer, else 1
    size_t need4 = fixed + (size_t)32 * 16 * N_ * 4 + (size_t)16 * N_ * N_ * 2;
    int nb = (ws_size >= need4) ? 4 : 1;
    int SH = nb * H_;
    float* degp = (float*)w;                   w += (size_t)32 * SH * N_ * 4;
    unsigned short* Wbuf = (unsigned short*)w;

    conv_kernel <<<1792, 256, 0, stream>>>(nf, Wl, Wq, Wk, nfb, Wt);
    gemm3_kernel<<<dim3(128, 4, 3), 256, 0, stream>>>(nfb, Wt, bl, qb, kb, Xt);

    for (int b0 = 0; b0 < B_; b0 += nb) {
        size_t xoff = (size_t)b0 * H_ * HD_ * N_;
        att_kernel   <<<dim3(16, 16, SH), 256, 0, stream>>>(adj, qb, kb, Wbuf, degp, b0, SH);
        degsum_kernel<<<SH * N_ / 256, 256, 0, stream>>>(degp, dis, b0, SH);
        scale_kernel <<<SH * HD_ * N_ / 8 / 256, 256, 0, stream>>>(Xt + xoff, dis + (size_t)b0 * H_ * N_, Xs + xoff);
        yout_kernel  <<<dim3(N_ / 16, nb), 1024, 0, stream>>>(Wbuf, Xs + xoff, dis, lng, lnb, out, b0);
    }
}

// Round 7
// 312.843 us; speedup vs baseline: 1.1227x; 1.1227x over previous
//
#include <hip/hip_runtime.h>
#include <hip/hip_bf16.h>

#define B_   4
#define N_   2048
#define IN_  256
#define OUT_ 256
#define H_   4
#define HD_  64
#define LN_EPS 1e-5f

typedef __bf16 bf16x8 __attribute__((ext_vector_type(8)));
typedef float  f32x4  __attribute__((ext_vector_type(4)));
typedef unsigned short u16x8 __attribute__((ext_vector_type(8)));
typedef unsigned int   u32x4 __attribute__((ext_vector_type(4)));

__device__ __forceinline__ unsigned short f2bf(float x) {
    unsigned int u = __float_as_uint(x);
    return (unsigned short)((u + 0x7FFFu + ((u >> 16) & 1u)) >> 16);
}
__device__ __forceinline__ float bf2f(unsigned short u) {
    return __uint_as_float((unsigned int)u << 16);
}
__device__ __forceinline__ unsigned int cvtpk(float lo, float hi) {
    unsigned int r;
    asm("v_cvt_pk_bf16_f32 %0, %1, %2" : "=v"(r) : "v"(lo), "v"(hi));
    return r;
}

// ---------------------------------------------------------------------------
// conv: nf -> bf16 (nfb), W_{lin,q,k} -> bf16 transposed (Wt[z][n][k])
// ---------------------------------------------------------------------------
__global__ __launch_bounds__(256) void conv_kernel(
    const float* __restrict__ nf, const float* __restrict__ Wl,
    const float* __restrict__ Wq, const float* __restrict__ Wk,
    unsigned short* __restrict__ nfb, unsigned short* __restrict__ Wt)
{
    const int bid = blockIdx.x, tid = threadIdx.x;
    if (bid < 1024) {
        size_t i = ((size_t)bid * 256 + tid) * 8;
        u16x8 o;
        #pragma unroll
        for (int j = 0; j < 8; j++) o[j] = f2bf(nf[i + j]);
        *(u16x8*)&nfb[i] = o;
    } else {
        int t = (bid - 1024) * 256 + tid;   // 0..196607
        int z = t >> 16;
        int l = t & 65535;
        int k = l & 255, n = l >> 8;
        const float* W = (z == 0) ? Wl : (z == 1 ? Wq : Wk);
        Wt[(size_t)z * 65536 + n * 256 + k] = f2bf(W[k * 256 + n]);
    }
}

// ---------------------------------------------------------------------------
// gemm3: X/q/k = lrelu(nfb @ W + bias), barrier-free fragment GEMM
// ---------------------------------------------------------------------------
__global__ __launch_bounds__(256) void gemm3_kernel(
    const unsigned short* __restrict__ nfb, const unsigned short* __restrict__ Wt3,
    const float* __restrict__ bl,
    unsigned short* __restrict__ qb, unsigned short* __restrict__ kb,
    unsigned short* __restrict__ Xt)
{
    const int z  = blockIdx.z;
    const int m0 = blockIdx.x * 64, n0 = blockIdx.y * 64;
    const int tid = threadIdx.x, wave = tid >> 6, lane = tid & 63;
    const int lq = lane >> 4, lr = lane & 15;
    const unsigned short* Wt = Wt3 + (size_t)z * 65536;

    f32x4 acc[4] = {};
    #pragma unroll 4
    for (int k0 = 0; k0 < IN_; k0 += 32) {
        bf16x8 af = *(const bf16x8*)&nfb[(size_t)(m0 + wave * 16 + lr) * IN_ + k0 + lq * 8];
        #pragma unroll
        for (int f = 0; f < 4; f++) {
            bf16x8 bfr = *(const bf16x8*)&Wt[(size_t)(n0 + f * 16 + lr) * IN_ + k0 + lq * 8];
            acc[f] = __builtin_amdgcn_mfma_f32_16x16x32_bf16(af, bfr, acc[f], 0, 0, 0);
        }
    }

    #pragma unroll
    for (int f = 0; f < 4; f++) {
        int c = n0 + f * 16 + lr;
        float bias = (z == 0) ? bl[c] : 0.0f;
        #pragma unroll
        for (int r = 0; r < 4; r++) {
            int m = m0 + wave * 16 + lq * 4 + r;
            float v = acc[f][r] + bias;
            v = (v >= 0.f) ? v : 0.01f * v;
            unsigned short bv = f2bf(v);
            if (z == 0) {
                int n = m & (N_ - 1);
                int h = c >> 6, d = c & 63;
                Xt[(((size_t)(m >> 11) * H_ + h) * HD_ + d) * N_ + n] = bv;
            } else {
                unsigned short* dst = (z == 1) ? qb : kb;
                dst[(size_t)m * OUT_ + c] = bv;
            }
        }
    }
}

// ---------------------------------------------------------------------------
// att (round-3 version, measured 109us): W = adj*sigmoid(q.k/8), row-sum
// partials. 128x128 tile, 4 waves 2x2, barrier-free.
// ---------------------------------------------------------------------------
__global__ __launch_bounds__(256) void att_kernel(
    const float* __restrict__ adj,
    const unsigned short* __restrict__ qb,
    const unsigned short* __restrict__ kb,
    unsigned short* __restrict__ W,      // chunk: [s_local][N][N]
    float* __restrict__ degp,            // [32][SH][N]
    int b_base, int SH)
{
    const int s  = blockIdx.z;
    const int bg = b_base + (s >> 2);
    const int hg = s & 3;
    const int x0 = blockIdx.x * 128, y0 = blockIdx.y * 128;
    const int tid = threadIdx.x, wave = tid >> 6, lane = tid & 63;
    const int lq = lane >> 4, lr = lane & 15;
    const int wq = wave >> 1, wn = wave & 1;
    const int wx0 = x0 + wq * 64, wy0 = y0 + wn * 64;
    const float sc = -0.125f * 1.44269504088896f;

    const unsigned short* qrow = qb + (size_t)(bg * N_ + wx0) * OUT_ + hg * HD_;
    const unsigned short* krow = kb + (size_t)(bg * N_ + wy0) * OUT_ + hg * HD_;

    f32x4 acc[4][4] = {};
    #pragma unroll
    for (int ks = 0; ks < 2; ks++) {
        bf16x8 af[4], bf[4];
        #pragma unroll
        for (int mf = 0; mf < 4; mf++)
            af[mf] = *(const bf16x8*)&qrow[(size_t)(mf * 16 + lr) * OUT_ + ks * 32 + lq * 8];
        #pragma unroll
        for (int nf = 0; nf < 4; nf++)
            bf[nf] = *(const bf16x8*)&krow[(size_t)(nf * 16 + lr) * OUT_ + ks * 32 + lq * 8];
        #pragma unroll
        for (int mf = 0; mf < 4; mf++)
            #pragma unroll
            for (int nf = 0; nf < 4; nf++)
                acc[mf][nf] = __builtin_amdgcn_mfma_f32_16x16x32_bf16(af[mf], bf[nf], acc[mf][nf], 0, 0, 0);
    }

    unsigned short* Wp = W + (size_t)s * N_ * N_;
    #pragma unroll
    for (int mf = 0; mf < 4; mf++) {
        #pragma unroll
        for (int r = 0; r < 4; r++) {
            int x = wx0 + mf * 16 + lq * 4 + r;
            const float* arow = adj + ((size_t)bg * N_ + x) * N_ + wy0;
            unsigned short* wrow = Wp + (size_t)x * N_ + wy0;
            float sum = 0.f;
            #pragma unroll
            for (int nf = 0; nf < 4; nf++) {
                float a = arow[nf * 16 + lr];
                float att = __builtin_amdgcn_rcpf(1.f + exp2f(acc[mf][nf][r] * sc));
                float wv = a * att;
                sum += wv;
                wrow[nf * 16 + lr] = f2bf(wv);
            }
            sum += __shfl_xor(sum, 1); sum += __shfl_xor(sum, 2);
            sum += __shfl_xor(sum, 4); sum += __shfl_xor(sum, 8);
            if (lr == 0)
                degp[((size_t)(blockIdx.y * 2 + wn) * SH + s) * N_ + x] = sum;
        }
    }
}

// ---------------------------------------------------------------------------
// degsum: deg = sum of 32 partials; dis = deg^-1/2
// ---------------------------------------------------------------------------
__global__ __launch_bounds__(256) void degsum_kernel(
    const float* __restrict__ degp, float* __restrict__ dis, int b_base, int SH)
{
    int t = blockIdx.x * 256 + threadIdx.x;    // SH*N threads
    int s = t >> 11, x = t & (N_ - 1);
    float sum = 0.f;
    #pragma unroll
    for (int j = 0; j < 32; j++) sum += degp[((size_t)j * SH + s) * N_ + x];
    dis[((size_t)b_base * H_ + s) * N_ + x] = (sum > 0.f) ? rsqrtf(sum) : 0.f;
}

// ---------------------------------------------------------------------------
// scale: Xs = Xt * dis_y (bf16); pointers pre-offset to chunk
// ---------------------------------------------------------------------------
__global__ __launch_bounds__(256) void scale_kernel(
    const unsigned short* __restrict__ Xt, const float* __restrict__ dis,
    unsigned short* __restrict__ Xs)
{
    int t = blockIdx.x * 256 + threadIdx.x;
    size_t idx = (size_t)t * 8;
    int s = t >> 14;                         // HD*N/8 = 16384
    int y = (int)(idx & (N_ - 1));
    f32x4 d0 = *(const f32x4*)&dis[(size_t)s * N_ + y];
    f32x4 d1 = *(const f32x4*)&dis[(size_t)s * N_ + y + 4];
    u16x8 x = *(const u16x8*)&Xt[idx];
    u32x4 o;
    o[0] = cvtpk(bf2f(x[0]) * d0[0], bf2f(x[1]) * d0[1]);
    o[1] = cvtpk(bf2f(x[2]) * d0[2], bf2f(x[3]) * d0[3]);
    o[2] = cvtpk(bf2f(x[4]) * d1[0], bf2f(x[5]) * d1[1]);
    o[3] = cvtpk(bf2f(x[6]) * d1[2], bf2f(x[7]) * d1[3]);
    *(u32x4*)&Xs[idx] = o;
}

// ---------------------------------------------------------------------------
// yout-v3: Yraw = dis_x * (W @ Xs), LDS-staged double-buffered GEMM.
// 512-thr blocks, x-tile 32, K-step 256. Staging: 512B-contiguous segments
// (16 thr x 32B per row). XOR-swizzled LDS, ds_read_b128 A-frags.
// ---------------------------------------------------------------------------
__global__ __launch_bounds__(512) void yout_kernel(
    const unsigned short* __restrict__ W,    // chunk base [s][N][N]
    const unsigned short* __restrict__ Xs,   // chunk base [s][64][N]
    const float* __restrict__ dis,           // full
    float* __restrict__ Yraw,                // full [B][N][256]
    int b_base)
{
    const int s  = blockIdx.y;               // local slice
    const int bg = b_base + (s >> 2);
    const int hg = s & 3;
    const int x0 = blockIdx.x * 32;
    const int tid = threadIdx.x;
    const int wave = tid >> 6, lane = tid & 63;
    const int xw = wave >> 2, dq = wave & 3; // xw: 16-row group, dq: 16-col group
    const int lq = lane >> 4, lr = lane & 15;

    __shared__ unsigned short As[2][32 * 256];   // 2 x 16KB, XOR-swizzled rows

    // staging: row = tid>>4 (32 rows), kslot = tid&15 (32B each)
    const int srow = tid >> 4, kslot = tid & 15;
    const int swz  = (srow & 7) << 4;
    const unsigned short* Wrow =
        W + (size_t)s * N_ * N_ + (size_t)(x0 + srow) * N_ + kslot * 16;

    const unsigned short* Xp = Xs + ((size_t)s * HD_ + dq * 16 + lr) * N_;

    const int arow = xw * 16 + lr;
    const int arsw = (arow & 7) << 4;

    f32x4 Y = {};

    // prologue: stage kt=0 into buf0
    {
        u16x8 r0 = *(const u16x8*)&Wrow[0];
        u16x8 r1 = *(const u16x8*)&Wrow[8];
        char* base = (char*)&As[0][0] + srow * 512;
        *(u16x8*)(base + ((kslot * 32) ^ swz))      = r0;
        *(u16x8*)(base + ((kslot * 32 + 16) ^ swz)) = r1;
    }
    __syncthreads();

    int cur = 0;
    for (int kt = 0; kt < 8; kt++) {
        // issue next-tile global loads early (latency hides under compute)
        u16x8 n0, n1;
        if (kt < 7) {
            n0 = *(const u16x8*)&Wrow[(kt + 1) * 256];
            n1 = *(const u16x8*)&Wrow[(kt + 1) * 256 + 8];
        }
        // compute on cur
        const char* abase = (const char*)&As[cur][0] + arow * 512;
        #pragma unroll
        for (int half = 0; half < 2; half++) {
            bf16x8 xf[4];
            #pragma unroll
            for (int u = 0; u < 4; u++)
                xf[u] = *(const bf16x8*)&Xp[kt * 256 + (half * 4 + u) * 32 + lq * 8];
            #pragma unroll
            for (int u = 0; u < 4; u++) {
                const int kb = ((half * 4 + u) * 32 + lq * 8) * 2;
                bf16x8 af = *(const bf16x8*)(abase + (kb ^ arsw));
                Y = __builtin_amdgcn_mfma_f32_16x16x32_bf16(af, xf[u], Y, 0, 0, 0);
            }
        }
        // write staged regs into the other buffer
        if (kt < 7) {
            char* base = (char*)&As[cur ^ 1][0] + srow * 512;
            *(u16x8*)(base + ((kslot * 32) ^ swz))      = n0;
            *(u16x8*)(base + ((kslot * 32 + 16) ^ swz)) = n1;
        }
        __syncthreads();
        cur ^= 1;
    }

    // epilogue: apply dis_x, store raw Y (LN in a separate pass)
    #pragma unroll
    for (int r = 0; r < 4; r++) {
        int x = x0 + xw * 16 + lq * 4 + r;
        float dx = dis[((size_t)bg * H_ + hg) * N_ + x];
        Yraw[((size_t)(bg * N_ + x)) * OUT_ + hg * HD_ + dq * 16 + lr] = Y[r] * dx;
    }
}

// ---------------------------------------------------------------------------
// ln: LayerNorm over 256 cols per row
// ---------------------------------------------------------------------------
__global__ __launch_bounds__(256) void ln_kernel(
    const float* __restrict__ Yraw,
    const float* __restrict__ lng, const float* __restrict__ lnb,
    float* __restrict__ out)
{
    const int row = blockIdx.x;
    const int c = threadIdx.x;
    const size_t base = (size_t)row * OUT_ + c;
    float v = Yraw[base];

    float s1 = v, s2 = v * v;
    #pragma unroll
    for (int d = 1; d < 64; d <<= 1) { s1 += __shfl_xor(s1, d); s2 += __shfl_xor(s2, d); }
    __shared__ float red[2][4];
    if ((c & 63) == 0) { red[0][c >> 6] = s1; red[1][c >> 6] = s2; }
    __syncthreads();
    float t1 = red[0][0] + red[0][1] + red[0][2] + red[0][3];
    float t2 = red[1][0] + red[1][1] + red[1][2] + red[1][3];
    float mu  = t1 * (1.f / 256.f);
    float var = t2 * (1.f / 256.f) - mu * mu;
    float rs  = rsqrtf(var + LN_EPS);
    out[base] = (v - mu) * rs * lng[c] + lnb[c];
}

extern "C" void kernel_launch(void* const* d_in, const int* in_sizes, int n_in,
                              void* d_out, int out_size, void* d_ws, size_t ws_size,
                              hipStream_t stream) {
    const float* nf  = (const float*)d_in[0];
    const float* adj = (const float*)d_in[1];
    const float* Wl  = (const float*)d_in[2];
    const float* bl  = (const float*)d_in[3];
    const float* Wq  = (const float*)d_in[4];
    const float* Wk  = (const float*)d_in[5];
    const float* lng = (const float*)d_in[6];
    const float* lnb = (const float*)d_in[7];
    float* out = (float*)d_out;

    char* w = (char*)d_ws;
    unsigned short* nfb = (unsigned short*)w;  w += (size_t)B_ * N_ * IN_ * 2;
    unsigned short* Wt  = (unsigned short*)w;  w += (size_t)3 * IN_ * OUT_ * 2;
    unsigned short* qb  = (unsigned short*)w;  w += (size_t)B_ * N_ * OUT_ * 2;
    unsigned short* kb  = (unsigned short*)w;  w += (size_t)B_ * N_ * OUT_ * 2;
    unsigned short* Xt  = (unsigned short*)w;  w += (size_t)B_ * N_ * OUT_ * 2;
    unsigned short* Xs  = (unsigned short*)w;  w += (size_t)B_ * N_ * OUT_ * 2;
    float* dis  = (float*)w;                   w += (size_t)B_ * H_ * N_ * 4;
    float* Yraw = (float*)w;                   w += (size_t)B_ * N_ * OUT_ * 4;  // 8.4MB
    size_t fixed = (size_t)(w - (char*)d_ws);

    // nb batches per chunk: 4 if ws fits the full 134MB W buffer, else 1
    size_t need4 = fixed + (size_t)32 * 16 * N_ * 4 + (size_t)16 * N_ * N_ * 2;
    int nb = (ws_size >= need4) ? 4 : 1;
    int SH = nb * H_;
    float* degp = (float*)w;                   w += (size_t)32 * SH * N_ * 4;
    unsigned short* Wbuf = (unsigned short*)w;

    conv_kernel <<<1792, 256, 0, stream>>>(nf, Wl, Wq, Wk, nfb, Wt);
    gemm3_kernel<<<dim3(128, 4, 3), 256, 0, stream>>>(nfb, Wt, bl, qb, kb, Xt);

    for (int b0 = 0; b0 < B_; b0 += nb) {
        size_t xoff = (size_t)b0 * H_ * HD_ * N_;
        att_kernel   <<<dim3(16, 16, SH), 256, 0, stream>>>(adj, qb, kb, Wbuf, degp, b0, SH);
        degsum_kernel<<<SH * N_ / 256, 256, 0, stream>>>(degp, dis, b0, SH);
        scale_kernel <<<SH * HD_ * N_ / 8 / 256, 256, 0, stream>>>(Xt + xoff, dis + (size_t)b0 * H_ * N_, Xs + xoff);
        yout_kernel  <<<dim3(N_ / 32, SH), 512, 0, stream>>>(Wbuf, Xs + xoff, dis, Yraw, b0);
    }
    ln_kernel<<<B_ * N_, 256, 0, stream>>>(Yraw, lng, lnb, out);
}